// Round 2
// baseline (92.437 us; speedup 1.0000x reference)
//
#include <hip/hip_runtime.h>

// PTS loss: B=32, N=2048.
//   non-sym batch: sum_n ||R_e p_n - R_g p_n||^2
//   sym batch:     sum_n min_m ||R_e p_n - R_g p_m||^2
// out = (sum_s + sum_p) / (2*N*B), single f32 scalar.
//
// R7: single fused kernel. Key insight: all 2048 rotated gt-candidates fit
// in 32 KB LDS (2048 x float4 with yy folded in), so every block can compute
// the COMPLETE min for its x-chunk locally — no cross-block min, no partial
// array (saves 8 MB HBM round-trip), no second kernel, no workspace at all.
// One atomicAdd per block (512 total). Output zeroed by hipMemsetAsync
// (stream-ordered, graph-capture safe — harness itself enqueues memsets).
// R6 lesson: occupancy tuning was a no-op; the cost is structure/overhead,
// not VALU throughput. R4 lesson: no device-scope fences (cost 56us).

#define NPTS  2048
#define NC    16              // x-chunks per batch -> 512 blocks total
#define TPB   128             // = NPTS/NC, one x-point per thread
#define YPT   (NPTS / TPB)    // 16 y-candidates staged per thread

static_assert(NPTS / NC == TPB, "one x-point per thread");

__device__ __forceinline__ void quat2mat(const float* __restrict__ q, float R[9]) {
    float w = q[0], x = q[1], y = q[2], z = q[3];
    float inv = 1.0f / sqrtf(w*w + x*x + y*y + z*z);
    w *= inv; x *= inv; y *= inv; z *= inv;
    R[0] = 1.f - 2.f*(y*y + z*z); R[1] = 2.f*(x*y - w*z);       R[2] = 2.f*(x*z + w*y);
    R[3] = 2.f*(x*y + w*z);       R[4] = 1.f - 2.f*(x*x + z*z); R[5] = 2.f*(y*z - w*x);
    R[6] = 2.f*(x*z - w*y);       R[7] = 2.f*(y*z + w*x);       R[8] = 1.f - 2.f*(x*x + y*y);
}

__device__ __forceinline__ float block_reduce_add(float v, float* red) {
    #pragma unroll
    for (int off = 32; off > 0; off >>= 1)
        v += __shfl_down(v, off, 64);
    const int tid = threadIdx.x;
    if ((tid & 63) == 0) red[tid >> 6] = v;
    __syncthreads();
    return red[0] + red[1];
}

__global__ __launch_bounds__(TPB) void pts_loss_fused(
    const float* __restrict__ q_est, const float* __restrict__ q_gt,
    const float* __restrict__ pts, const int* __restrict__ symmetries,
    float* __restrict__ out, float scale)
{
    const int b   = blockIdx.x;   // batch (fastest-varying -> sym/non-sym
    const int c   = blockIdx.y;   //   blocks interleave across CUs)
    const int tid = threadIdx.x;

    __shared__ float4 ybuf[NPTS];     // 32 KB: all candidates of this batch
    __shared__ float  red[TPB / 64];

    const bool is_sym = symmetries[b] != 0;   // block-uniform
    const float* pb = pts + (size_t)b * NPTS * 3;

    float Re[9], Rg[9];
    quat2mat(q_est + 4*b, Re);
    quat2mat(q_gt  + 4*b, Rg);

    // this thread's x-point
    const int   n  = c * TPB + tid;
    const float p0 = pb[3*n+0], p1 = pb[3*n+1], p2 = pb[3*n+2];

    float s;
    if (!is_sym) {
        float d0 = (Re[0]-Rg[0])*p0 + (Re[1]-Rg[1])*p1 + (Re[2]-Rg[2])*p2;
        float d1 = (Re[3]-Rg[3])*p0 + (Re[4]-Rg[4])*p1 + (Re[5]-Rg[5])*p2;
        float d2 = (Re[6]-Rg[6])*p0 + (Re[7]-Rg[7])*p1 + (Re[8]-Rg[8])*p2;
        s = d0*d0 + d1*d1 + d2*d2;
    } else {
        // stage ALL 2048 candidates: y = Rg p_m, w-slot = |y|^2
        #pragma unroll
        for (int k = 0; k < YPT; ++k) {
            int m = k * TPB + tid;
            float a0 = pb[3*m+0], a1 = pb[3*m+1], a2 = pb[3*m+2];
            float y0 = Rg[0]*a0 + Rg[1]*a1 + Rg[2]*a2;
            float y1 = Rg[3]*a0 + Rg[4]*a1 + Rg[5]*a2;
            float y2 = Rg[6]*a0 + Rg[7]*a1 + Rg[8]*a2;
            ybuf[m] = make_float4(y0, y1, y2, y0*y0 + y1*y1 + y2*y2);
        }
        __syncthreads();

        float x0 = Re[0]*p0 + Re[1]*p1 + Re[2]*p2;
        float x1 = Re[3]*p0 + Re[4]*p1 + Re[5]*p2;
        float x2 = Re[6]*p0 + Re[7]*p1 + Re[8]*p2;
        float nx0 = -2.f*x0, nx1 = -2.f*x1, nx2 = -2.f*x2;
        float xx  = x0*x0 + x1*x1 + x2*x2;

        // complete min over all 2048 candidates; 4 independent chains for ILP
        float m0 = 1e30f, m1 = 1e30f, m2 = 1e30f, m3 = 1e30f;
        #pragma unroll 2
        for (int m = 0; m < NPTS; m += 4) {
            float4 ya = ybuf[m+0];
            float4 yb = ybuf[m+1];
            float4 yc = ybuf[m+2];
            float4 yd = ybuf[m+3];
            m0 = fminf(m0, fmaf(nx0, ya.x, fmaf(nx1, ya.y, fmaf(nx2, ya.z, ya.w))));
            m1 = fminf(m1, fmaf(nx0, yb.x, fmaf(nx1, yb.y, fmaf(nx2, yb.z, yb.w))));
            m2 = fminf(m2, fmaf(nx0, yc.x, fmaf(nx1, yc.y, fmaf(nx2, yc.z, yc.w))));
            m3 = fminf(m3, fmaf(nx0, yd.x, fmaf(nx1, yd.y, fmaf(nx2, yd.z, yd.w))));
        }
        s = xx + fminf(fminf(m0, m1), fminf(m2, m3));
    }

    s = block_reduce_add(s, red);
    if (tid == 0) atomicAdd(out, s * scale);
}

extern "C" void kernel_launch(void* const* d_in, const int* in_sizes, int n_in,
                              void* d_out, int out_size, void* d_ws, size_t ws_size,
                              hipStream_t stream) {
    const float* q_est = (const float*)d_in[0];
    const float* q_gt  = (const float*)d_in[1];
    // d_in[2] = T, unused by the reference
    const float* pts   = (const float*)d_in[3];
    const int*   sym   = (const int*)d_in[4];
    float* out = (float*)d_out;

    const int B = in_sizes[0] / 4;  // 32
    const float scale = 1.0f / (2.0f * (float)NPTS * (float)B);

    hipMemsetAsync(out, 0, sizeof(float), stream);
    dim3 grid(B, NC);
    pts_loss_fused<<<grid, TPB, 0, stream>>>(q_est, q_gt, pts, sym, out, scale);
}

// Round 4
// 77.849 us; speedup vs baseline: 1.1874x; 1.1874x over previous
//
#include <hip/hip_runtime.h>

// PTS loss: B=32, N=2048.
//   non-sym batch: sum_n ||R_e p_n - R_g p_n||^2
//   sym batch:     sum_n min_m ||R_e p_n - R_g p_m||^2
// out = (sum_s + sum_p) / (2*N*B), single f32 scalar.
//
// R9 = R8 with the non-sym 8x-overcount fixed: in R8 all 8 waves computed
// the SAME 128 points (lane-based index, no wave term) and the block sum
// counted them 8x. Now only tid<CHUNK threads contribute (1 pt/thread).
// Sym path unchanged from R8 (wave-duplicated x-fragments are intentional:
// each wave mins its own 256-candidate m-range, combined via LDS atomicMin
// on order-preserving uint encoding — no double-count by construction).
// Structure: single launch, block=(batch, 128-pt x-chunk), 8 waves, all
// 2048 rotated candidates in 32 KB LDS. Per-wave critical path ~256 iters.
// Ledger: R4 device-fence fuse -56us; R7 per-thread full-m chain -17us;
// R6 occupancy tune +-0; R8 non-sym overcount = FAIL. Fixed floor: ~40us
// harness ws-poison fill + ~23us launch/replay overhead.

#define NPTS  2048
#define TPB   512
#define NW    (TPB / 64)       // 8 waves
#define PX    2                // x-points per lane-slot (sym path)
#define CHUNK (64 * PX)        // 128 x-points per block
#define NCX   (NPTS / CHUNK)   // 16 x-chunk blocks per batch
#define MR    (NPTS / NW)      // 256 candidates per wave
#define SPT   (NPTS / TPB)     // 4 candidates staged per thread

__device__ __forceinline__ void quat2mat(const float* __restrict__ q, float R[9]) {
    float w = q[0], x = q[1], y = q[2], z = q[3];
    float inv = 1.0f / sqrtf(w*w + x*x + y*y + z*z);
    w *= inv; x *= inv; y *= inv; z *= inv;
    R[0] = 1.f - 2.f*(y*y + z*z); R[1] = 2.f*(x*y - w*z);       R[2] = 2.f*(x*z + w*y);
    R[3] = 2.f*(x*y + w*z);       R[4] = 1.f - 2.f*(x*x + z*z); R[5] = 2.f*(y*z - w*x);
    R[6] = 2.f*(x*z - w*y);       R[7] = 2.f*(y*z + w*x);       R[8] = 1.f - 2.f*(x*x + y*y);
}

// order-preserving float<->uint (correct for negative values too)
__device__ __forceinline__ unsigned fenc(float f) {
    unsigned u = __float_as_uint(f);
    return u ^ (unsigned)(((int)u >> 31) | 0x80000000);
}
__device__ __forceinline__ float fdec(unsigned e) {
    unsigned u = (e & 0x80000000u) ? (e ^ 0x80000000u) : ~e;
    return __uint_as_float(u);
}

__device__ __forceinline__ float block_reduce_add(float v, float* red) {
    #pragma unroll
    for (int off = 32; off > 0; off >>= 1)
        v += __shfl_down(v, off, 64);
    const int tid = threadIdx.x;
    if ((tid & 63) == 0) red[tid >> 6] = v;
    __syncthreads();
    float s = 0.f;
    #pragma unroll
    for (int w = 0; w < NW; ++w) s += red[w];
    return s;
}

__global__ __launch_bounds__(TPB) void pts_loss(
    const float* __restrict__ q_est, const float* __restrict__ q_gt,
    const float* __restrict__ pts, const int* __restrict__ symmetries,
    float* __restrict__ out, float scale)
{
    const int b    = blockIdx.x;
    const int c    = blockIdx.y;
    const int tid  = threadIdx.x;
    const int lane = tid & 63;
    const int w    = tid >> 6;

    __shared__ float4   ybuf[NPTS];    // 32 KB: all rotated candidates
    __shared__ unsigned dmin[CHUNK];   // 512 B: cross-wave min combine
    __shared__ float    red[NW];

    const bool is_sym = symmetries[b] != 0;   // block-uniform
    const float* pb = pts + (size_t)b * NPTS * 3;

    float Re[9], Rg[9];
    quat2mat(q_est + 4*b, Re);
    quat2mat(q_gt  + 4*b, Rg);

    if (!is_sym) {
        // ONE point per thread, only tid<CHUNK contribute (R8 bug: all 8
        // waves computed the same 128 points -> 8x overcount).
        float s = 0.f;
        if (tid < CHUNK) {
            int n = c * CHUNK + tid;
            float p0 = pb[3*n+0], p1 = pb[3*n+1], p2 = pb[3*n+2];
            float d0 = (Re[0]-Rg[0])*p0 + (Re[1]-Rg[1])*p1 + (Re[2]-Rg[2])*p2;
            float d1 = (Re[3]-Rg[3])*p0 + (Re[4]-Rg[4])*p1 + (Re[5]-Rg[5])*p2;
            float d2 = (Re[6]-Rg[6])*p0 + (Re[7]-Rg[7])*p1 + (Re[8]-Rg[8])*p2;
            s = d0*d0 + d1*d1 + d2*d2;
        }
        s = block_reduce_add(s, red);
        if (tid == 0) atomicAdd(out, s * scale);
        return;
    }

    // init cross-wave min slots (ordered before use by the staging barrier)
    if (tid < CHUNK) dmin[tid] = 0xFFFFFFFFu;

    // stage ALL candidates: y = Rg p_m, w-slot = |y|^2  (4 per thread)
    #pragma unroll
    for (int j = 0; j < SPT; ++j) {
        int m = j * TPB + tid;
        float a0 = pb[3*m+0], a1 = pb[3*m+1], a2 = pb[3*m+2];
        float y0 = Rg[0]*a0 + Rg[1]*a1 + Rg[2]*a2;
        float y1 = Rg[3]*a0 + Rg[4]*a1 + Rg[5]*a2;
        float y2 = Rg[6]*a0 + Rg[7]*a1 + Rg[8]*a2;
        ybuf[m] = make_float4(y0, y1, y2, y0*y0 + y1*y1 + y2*y2);
    }
    __syncthreads();

    // my PX x-points (lane-determined; identical across the 8 waves ON
    // PURPOSE — each wave mins a different m-range for the same points)
    float nx0[PX], nx1[PX], nx2[PX], xx[PX], mins[PX];
    #pragma unroll
    for (int k = 0; k < PX; ++k) {
        int n = c * CHUNK + k * 64 + lane;
        float p0 = pb[3*n+0], p1 = pb[3*n+1], p2 = pb[3*n+2];
        float x0 = Re[0]*p0 + Re[1]*p1 + Re[2]*p2;
        float x1 = Re[3]*p0 + Re[4]*p1 + Re[5]*p2;
        float x2 = Re[6]*p0 + Re[7]*p1 + Re[8]*p2;
        nx0[k] = -2.f*x0; nx1[k] = -2.f*x1; nx2[k] = -2.f*x2;
        xx[k]  = x0*x0 + x1*x1 + x2*x2;
        mins[k] = 1e30f;
    }

    // min over THIS WAVE's m-range only (256 candidates, broadcast reads)
    const int mbase = w * MR;
    #pragma unroll 4
    for (int i = 0; i < MR; ++i) {
        float4 y = ybuf[mbase + i];
        #pragma unroll
        for (int k = 0; k < PX; ++k) {
            float t = fmaf(nx0[k], y.x, fmaf(nx1[k], y.y, fmaf(nx2[k], y.z, y.w)));
            mins[k] = fminf(mins[k], t);
        }
    }

    // fold xx (identical across waves for the same point) and combine
    #pragma unroll
    for (int k = 0; k < PX; ++k)
        atomicMin(&dmin[k * 64 + lane], fenc(mins[k] + xx[k]));
    __syncthreads();

    float s = (tid < CHUNK) ? fdec(dmin[tid]) : 0.f;
    s = block_reduce_add(s, red);
    if (tid == 0) atomicAdd(out, s * scale);
}

extern "C" void kernel_launch(void* const* d_in, const int* in_sizes, int n_in,
                              void* d_out, int out_size, void* d_ws, size_t ws_size,
                              hipStream_t stream) {
    const float* q_est = (const float*)d_in[0];
    const float* q_gt  = (const float*)d_in[1];
    // d_in[2] = T, unused by the reference
    const float* pts   = (const float*)d_in[3];
    const int*   sym   = (const int*)d_in[4];
    float* out = (float*)d_out;

    const int B = in_sizes[0] / 4;  // 32
    const float scale = 1.0f / (2.0f * (float)NPTS * (float)B);

    hipMemsetAsync(out, 0, sizeof(float), stream);
    dim3 grid(B, NCX);
    pts_loss<<<grid, TPB, 0, stream>>>(q_est, q_gt, pts, sym, out, scale);
}

// Round 5
// 74.855 us; speedup vs baseline: 1.2349x; 1.0400x over previous
//
#include <hip/hip_runtime.h>

// PTS loss: B=32, N=2048.
//   non-sym batch: sum_n ||R_e p_n - R_g p_n||^2
//   sym batch:     sum_n min_m ||R_e p_n - R_g p_m||^2
// out = (sum_s + sum_p) / (2*N*B), single f32 scalar.
//
// R10: dispatch-structure round. R9 showed the hipMemsetAsync dispatch cost
// ~3us of replay time vs R5's in-kernel zero. Remove BOTH memset and
// atomics: kernel A writes one unscaled partial per block into ws (512
// floats, 2 KB, written-before-read so poison-safe, L2-resident); kernel B
// (1 block) sums them and OVERWRITES out = total*scale — no zero-init of
// out needed at all, no dependence on out-buffer initial contents.
// Sym math unchanged from R9 (wave-split m-ranges over 32 KB LDS candidate
// stage, LDS atomicMin combine via order-preserving uint encoding).
// Ledger: R4 device-fence fuse -56us; R7 per-thread full-m chain -17us;
// R6 occupancy tune +-0; R8 non-sym 8x overcount FAIL; R9 memset dispatch
// -3us. Fixed floor: ~40us harness 256-MiB ws-poison fill (present even
// when ws unused) + ~30us launch/replay overhead.

#define NPTS  2048
#define TPB   512
#define NW    (TPB / 64)       // 8 waves
#define PX    2                // x-points per lane-slot (sym path)
#define CHUNK (64 * PX)        // 128 x-points per block
#define NCX   (NPTS / CHUNK)   // 16 x-chunk blocks per batch
#define MR    (NPTS / NW)      // 256 candidates per wave
#define SPT   (NPTS / TPB)     // 4 candidates staged per thread

__device__ __forceinline__ void quat2mat(const float* __restrict__ q, float R[9]) {
    float w = q[0], x = q[1], y = q[2], z = q[3];
    float inv = 1.0f / sqrtf(w*w + x*x + y*y + z*z);
    w *= inv; x *= inv; y *= inv; z *= inv;
    R[0] = 1.f - 2.f*(y*y + z*z); R[1] = 2.f*(x*y - w*z);       R[2] = 2.f*(x*z + w*y);
    R[3] = 2.f*(x*y + w*z);       R[4] = 1.f - 2.f*(x*x + z*z); R[5] = 2.f*(y*z - w*x);
    R[6] = 2.f*(x*z - w*y);       R[7] = 2.f*(y*z + w*x);       R[8] = 1.f - 2.f*(x*x + y*y);
}

// order-preserving float<->uint (correct for negative values too)
__device__ __forceinline__ unsigned fenc(float f) {
    unsigned u = __float_as_uint(f);
    return u ^ (unsigned)(((int)u >> 31) | 0x80000000);
}
__device__ __forceinline__ float fdec(unsigned e) {
    unsigned u = (e & 0x80000000u) ? (e ^ 0x80000000u) : ~e;
    return __uint_as_float(u);
}

__device__ __forceinline__ float block_reduce_add(float v, float* red) {
    #pragma unroll
    for (int off = 32; off > 0; off >>= 1)
        v += __shfl_down(v, off, 64);
    const int tid = threadIdx.x;
    if ((tid & 63) == 0) red[tid >> 6] = v;
    __syncthreads();
    float s = 0.f;
    #pragma unroll
    for (int w = 0; w < NW; ++w) s += red[w];
    return s;
}

__global__ __launch_bounds__(TPB) void pts_loss_main(
    const float* __restrict__ q_est, const float* __restrict__ q_gt,
    const float* __restrict__ pts, const int* __restrict__ symmetries,
    float* __restrict__ partial)
{
    const int b    = blockIdx.x;
    const int c    = blockIdx.y;
    const int tid  = threadIdx.x;
    const int lane = tid & 63;
    const int w    = tid >> 6;

    __shared__ float4   ybuf[NPTS];    // 32 KB: all rotated candidates
    __shared__ unsigned dmin[CHUNK];   // 512 B: cross-wave min combine
    __shared__ float    red[NW];

    const bool is_sym = symmetries[b] != 0;   // block-uniform
    const float* pb = pts + (size_t)b * NPTS * 3;

    float Re[9], Rg[9];
    quat2mat(q_est + 4*b, Re);
    quat2mat(q_gt  + 4*b, Rg);

    if (!is_sym) {
        // ONE point per thread, only tid<CHUNK contribute (R8 lesson:
        // lane-indexed points + full-block sum = 8x overcount).
        float s = 0.f;
        if (tid < CHUNK) {
            int n = c * CHUNK + tid;
            float p0 = pb[3*n+0], p1 = pb[3*n+1], p2 = pb[3*n+2];
            float d0 = (Re[0]-Rg[0])*p0 + (Re[1]-Rg[1])*p1 + (Re[2]-Rg[2])*p2;
            float d1 = (Re[3]-Rg[3])*p0 + (Re[4]-Rg[4])*p1 + (Re[5]-Rg[5])*p2;
            float d2 = (Re[6]-Rg[6])*p0 + (Re[7]-Rg[7])*p1 + (Re[8]-Rg[8])*p2;
            s = d0*d0 + d1*d1 + d2*d2;
        }
        s = block_reduce_add(s, red);
        if (tid == 0) partial[b * NCX + c] = s;
        return;
    }

    // init cross-wave min slots (ordered before use by the staging barrier)
    if (tid < CHUNK) dmin[tid] = 0xFFFFFFFFu;

    // stage ALL candidates: y = Rg p_m, w-slot = |y|^2  (4 per thread)
    #pragma unroll
    for (int j = 0; j < SPT; ++j) {
        int m = j * TPB + tid;
        float a0 = pb[3*m+0], a1 = pb[3*m+1], a2 = pb[3*m+2];
        float y0 = Rg[0]*a0 + Rg[1]*a1 + Rg[2]*a2;
        float y1 = Rg[3]*a0 + Rg[4]*a1 + Rg[5]*a2;
        float y2 = Rg[6]*a0 + Rg[7]*a1 + Rg[8]*a2;
        ybuf[m] = make_float4(y0, y1, y2, y0*y0 + y1*y1 + y2*y2);
    }
    __syncthreads();

    // my PX x-points (lane-determined; identical across the 8 waves ON
    // PURPOSE — each wave mins a different m-range for the same points)
    float nx0[PX], nx1[PX], nx2[PX], xx[PX], mins[PX];
    #pragma unroll
    for (int k = 0; k < PX; ++k) {
        int n = c * CHUNK + k * 64 + lane;
        float p0 = pb[3*n+0], p1 = pb[3*n+1], p2 = pb[3*n+2];
        float x0 = Re[0]*p0 + Re[1]*p1 + Re[2]*p2;
        float x1 = Re[3]*p0 + Re[4]*p1 + Re[5]*p2;
        float x2 = Re[6]*p0 + Re[7]*p1 + Re[8]*p2;
        nx0[k] = -2.f*x0; nx1[k] = -2.f*x1; nx2[k] = -2.f*x2;
        xx[k]  = x0*x0 + x1*x1 + x2*x2;
        mins[k] = 1e30f;
    }

    // min over THIS WAVE's m-range only (256 candidates, broadcast reads)
    const int mbase = w * MR;
    #pragma unroll 4
    for (int i = 0; i < MR; ++i) {
        float4 y = ybuf[mbase + i];
        #pragma unroll
        for (int k = 0; k < PX; ++k) {
            float t = fmaf(nx0[k], y.x, fmaf(nx1[k], y.y, fmaf(nx2[k], y.z, y.w)));
            mins[k] = fminf(mins[k], t);
        }
    }

    // fold xx (identical across waves for the same point) and combine
    #pragma unroll
    for (int k = 0; k < PX; ++k)
        atomicMin(&dmin[k * 64 + lane], fenc(mins[k] + xx[k]));
    __syncthreads();

    float s = (tid < CHUNK) ? fdec(dmin[tid]) : 0.f;
    s = block_reduce_add(s, red);
    if (tid == 0) partial[b * NCX + c] = s;
}

// 1 block: sum the per-block partials and overwrite out (no zero-init dep).
__global__ __launch_bounds__(TPB) void pts_loss_final(
    const float* __restrict__ partial, float* __restrict__ out,
    int npart, float scale)
{
    const int tid = threadIdx.x;
    __shared__ float red[NW];
    float s = 0.f;
    for (int i = tid; i < npart; i += TPB)
        s += partial[i];
    s = block_reduce_add(s, red);
    if (tid == 0) *out = s * scale;
}

extern "C" void kernel_launch(void* const* d_in, const int* in_sizes, int n_in,
                              void* d_out, int out_size, void* d_ws, size_t ws_size,
                              hipStream_t stream) {
    const float* q_est = (const float*)d_in[0];
    const float* q_gt  = (const float*)d_in[1];
    // d_in[2] = T, unused by the reference
    const float* pts   = (const float*)d_in[3];
    const int*   sym   = (const int*)d_in[4];
    float* out = (float*)d_out;

    const int B = in_sizes[0] / 4;  // 32
    const float scale = 1.0f / (2.0f * (float)NPTS * (float)B);
    const int npart = B * NCX;      // 512

    float* partial = (float*)d_ws;  // 2 KB, written before read

    dim3 grid(B, NCX);
    pts_loss_main<<<grid, TPB, 0, stream>>>(q_est, q_gt, pts, sym, partial);
    pts_loss_final<<<1, TPB, 0, stream>>>(partial, out, npart, scale);
}